// Round 12
// baseline (158.195 us; speedup 1.0000x reference)
//
#include <hip/hip_runtime.h>
#include <hip/hip_bf16.h>

// ---------- types ----------
typedef float f32x4 __attribute__((ext_vector_type(4)));
typedef __bf16 bf16x8 __attribute__((ext_vector_type(8)));
typedef _Float16 f16x2 __attribute__((ext_vector_type(2)));
typedef _Float16 f16x4 __attribute__((ext_vector_type(4)));

// fp32 -> bf16 RNE
__device__ __forceinline__ unsigned short f2bf(float f){
  unsigned int u = __builtin_bit_cast(unsigned int, f);
  u += 0x7fffu + ((u >> 16) & 1u);
  return (unsigned short)(u >> 16);
}
__device__ __forceinline__ float bf2f(unsigned short h){
  return __builtin_bit_cast(float, (unsigned int)h << 16);
}

// packed f32x2 -> f16x2 (v_cvt_pkrtz_f16_f32), with type-identity fix
__device__ __forceinline__ f16x2 pkrtz(float a, float b){
  return __builtin_bit_cast(f16x2, __builtin_amdgcn_cvt_pkrtz(a, b));
}

__device__ __forceinline__ void glds16(const void* g, void* l){
  __builtin_amdgcn_global_load_lds((const __attribute__((address_space(1))) void*)g,
                                   (__attribute__((address_space(3))) void*)l, 16, 0, 0);
}

__device__ __forceinline__ f32x4 mfma16(bf16x8 a, bf16x8 b, f32x4 c){
  return __builtin_amdgcn_mfma_f32_16x16x32_bf16(a, b, c, 0, 0, 0);
}
__device__ __forceinline__ f32x4 mfma16h(f16x4 a, f16x4 b, f32x4 c){
  return __builtin_amdgcn_mfma_f32_16x16x16f16(a, b, c, 0, 0, 0);
}

#if __has_builtin(__builtin_amdgcn_exp2f)
__device__ __forceinline__ float exp2v(float x){ return __builtin_amdgcn_exp2f(x); }
#else
__device__ __forceinline__ float exp2v(float x){ return exp2f(x); }
#endif

// ---------- kernel: cvt3 (q/k/v fp32->bf16) + transW fused (y==3 slice) ----------
__global__ void cvt3t_kernel(const float* __restrict__ qs, const float* __restrict__ ks,
                             const float* __restrict__ vs, unsigned short* __restrict__ dst,
                             const float* __restrict__ Wq, const float* __restrict__ Wk,
                             const float* __restrict__ Wv, const float* __restrict__ Wo,
                             unsigned short* __restrict__ WT){
  if(blockIdx.y == 3){
    // transW: W[1024][1024] f32 -> W^T bf16 (Wq scaled by 0.125*log2e)
    if(blockIdx.x >= 1024) return;
    const int wsel = blockIdx.x >> 8, bx = blockIdx.x & 255;
    const float* W = (wsel==0)?Wq:(wsel==1)?Wk:(wsel==2)?Wv:Wo;
    const float scale = (wsel==0) ? 0.1803368801111601f : 1.0f;
    unsigned short* D = WT + (size_t)wsel * 1048576;
    int r0 = (bx >> 4) * 64, c0 = (bx & 15) * 64;
    __shared__ unsigned short T[64][65];
    int t = threadIdx.x;
    {
      int r = t >> 2, cb = (t & 3) * 16;
      const float4* src = (const float4*)(W + (size_t)(r0 + r) * 1024 + (c0 + cb));
      float4 v0 = src[0], v1 = src[1], v2 = src[2], v3 = src[3];
      float vals[16] = {v0.x,v0.y,v0.z,v0.w, v1.x,v1.y,v1.z,v1.w,
                        v2.x,v2.y,v2.z,v2.w, v3.x,v3.y,v3.z,v3.w};
      #pragma unroll
      for(int j=0;j<16;j++) T[cb + j][r] = f2bf(vals[j] * scale);
    }
    __syncthreads();
    {
      int c = t >> 2, rb = (t & 3) * 16;
      union { unsigned short h[16]; uint4 v[2]; } o;
      #pragma unroll
      for(int j=0;j<16;j++) o.h[j] = T[c][rb + j];
      uint4* dp = (uint4*)(D + (size_t)(c0 + c) * 1024 + (r0 + rb));
      dp[0] = o.v[0]; dp[1] = o.v[1];
    }
    return;
  }
  const float* src = (blockIdx.y==0)?qs:(blockIdx.y==1)?ks:vs;
  unsigned short* d = dst + (size_t)blockIdx.y * 4194304;
  int i = blockIdx.x * 256 + threadIdx.x;
  const float4* s = (const float4*)src;
  float4 a = s[2*i], b = s[2*i+1];
  union { unsigned short h[8]; uint4 v; } o;
  o.h[0]=f2bf(a.x); o.h[1]=f2bf(a.y); o.h[2]=f2bf(a.z); o.h[3]=f2bf(a.w);
  o.h[4]=f2bf(b.x); o.h[5]=f2bf(b.y); o.h[6]=f2bf(b.z); o.h[7]=f2bf(b.w);
  ((uint4*)d)[i] = o.v;
}

// ---------- kernel: C[M=4096][N=1024] = A @ BT^T, bf16, 128x128 tile, BK=64 ----------
// (round-8 proven single-buffer version)
// blockIdx.z==2 writes per-head transposed V as F16: Vt[(b*16+h)*64+d][s].
// blockIdx.z==3 (OUTF32==0 launch only): pack_mask slice (self-detecting dtype),
// overlapping the mask's HBM reads with the GEMM's compute.
template<int OUTF32>
__global__ __launch_bounds__(256,2) void gemm_bt(
    const unsigned short* __restrict__ A0, const unsigned short* __restrict__ A1, const unsigned short* __restrict__ A2,
    const unsigned short* __restrict__ B0, const unsigned short* __restrict__ B1, const unsigned short* __restrict__ B2,
    unsigned short* __restrict__ C0, unsigned short* __restrict__ C1, unsigned short* __restrict__ C2,
    float* __restrict__ Cf,
    const unsigned char* __restrict__ mask8, unsigned int* __restrict__ mp)
{
  if(OUTF32 == 0 && blockIdx.z == 3){
    // pack mask into bits: mp[row][64 words]; 16 rows per block, 4 per wave.
    const int idx = blockIdx.y * 32 + blockIdx.x;      // 0..255
    const int wid = threadIdx.x >> 6, lane = threadIdx.x & 63;
    const unsigned int* w32 = (const unsigned int*)mask8;
    int bad = 0;
    #pragma unroll
    for(int c = 0; c < 1024; c += 64) bad |= (w32[c + lane] > 1u);
    const int is32 = !__any(bad);
    const int* m32 = (const int*)mask8;
    for(int rr = 0; rr < 4; ++rr){
      const int row = idx*16 + wid*4 + rr;
      for(int c0 = 0; c0 < 2048; c0 += 64){
        int mv = is32 ? m32[(size_t)row*2048 + c0 + lane]
                      : (int)mask8[(size_t)row*2048 + c0 + lane];
        unsigned long long bm = __ballot(mv != 0);
        if(lane == 0){
          mp[(size_t)row*64 + (c0 >> 5)]     = (unsigned int)bm;
          mp[(size_t)row*64 + (c0 >> 5) + 1] = (unsigned int)(bm >> 32);
        }
      }
    }
    return;
  }
  const unsigned short* A  = (blockIdx.z==0)?A0:(blockIdx.z==1)?A1:A2;
  const unsigned short* BT = (blockIdx.z==0)?B0:(blockIdx.z==1)?B1:B2;
  unsigned short* C        = (blockIdx.z==0)?C0:(blockIdx.z==1)?C1:C2;
  __shared__ unsigned short Asm[128*64];
  __shared__ unsigned short Bsm[128*64];
  const int wid = threadIdx.x >> 6, lane = threadIdx.x & 63;
  const int m0 = blockIdx.x * 128, n0 = blockIdx.y * 128;
  const int wrow = wid >> 1, wcol = wid & 1;
  const int li = lane & 15, lg = lane >> 4, li7 = lane & 7;
  f32x4 acc[4][4] = {};
  const int sr = lane >> 3;       // 0..7 (row within 8-row chunk)
  const int sc = lane & 7;        // 0..7 (16B block within 128B row)

  for(int kt = 0; kt < 16; ++kt){
    const int kofs = kt * 64;
    #pragma unroll
    for(int i=0;i<4;i++){
      int r = wid*32 + i*8 + sr;
      int blk = sc ^ sr;
      glds16(A  + (size_t)(m0 + r)*1024 + kofs + blk*8, &Asm[(wid*32 + i*8)*64]);
      glds16(BT + (size_t)(n0 + r)*1024 + kofs + blk*8, &Bsm[(wid*32 + i*8)*64]);
    }
    __syncthreads();
    #pragma unroll
    for(int kk=0; kk<2; kk++){
      bf16x8 af[4], bfv[4];
      #pragma unroll
      for(int fm=0; fm<4; fm++){
        int row = wrow*64 + fm*16 + li;
        int blk = (kk*4 + lg) ^ li7;
        af[fm] = *(const bf16x8*)&Asm[row*64 + blk*8];
      }
      #pragma unroll
      for(int fn=0; fn<4; fn++){
        int row = wcol*64 + fn*16 + li;
        int blk = (kk*4 + lg) ^ li7;
        bfv[fn] = *(const bf16x8*)&Bsm[row*64 + blk*8];
      }
      __builtin_amdgcn_s_setprio(1);
      #pragma unroll
      for(int fm=0; fm<4; fm++)
        #pragma unroll
        for(int fn=0; fn<4; fn++)
          acc[fm][fn] = mfma16(af[fm], bfv[fn], acc[fm][fn]);
      __builtin_amdgcn_s_setprio(0);
    }
    __syncthreads();
  }
  if(OUTF32 == 0 && blockIdx.z == 2){
    #pragma unroll
    for(int fm=0; fm<4; fm++){
      #pragma unroll
      for(int fn=0; fn<4; fn++){
        int col  = n0 + wcol*64 + fn*16 + li;        // h*64 + d
        int rowb = m0 + wrow*64 + fm*16 + lg*4;      // b*2048 + s
        int bq = rowb >> 11, s = rowb & 2047;
        union { f16x2 h2[2]; unsigned long long u; } o;
        o.h2[0] = pkrtz(acc[fm][fn][0], acc[fm][fn][1]);
        o.h2[1] = pkrtz(acc[fm][fn][2], acc[fm][fn][3]);
        *(unsigned long long*)&C[((size_t)(bq*16 + (col>>6))*64 + (col&63))*2048 + s] = o.u;
      }
    }
  } else {
    #pragma unroll
    for(int fm=0; fm<4; fm++){
      #pragma unroll
      for(int fn=0; fn<4; fn++){
        int col  = n0 + wcol*64 + fn*16 + li;
        int rowb = m0 + wrow*64 + fm*16 + lg*4;
        #pragma unroll
        for(int r=0;r<4;r++){
          if(OUTF32) Cf[(size_t)(rowb + r)*1024 + col] = acc[fm][fn][r];
          else       C [(size_t)(rowb + r)*1024 + col] = f2bf(acc[fm][fn][r]);
        }
      }
    }
  }
}

// ---------- kernel: flash attention v7 (round-8 proven version, unchanged) ----------
// 16x16 swapped-QK, fixed-exponent softmax, 2 q-tiles per wave (32 q-rows),
// PV via mfma_f32_16x16x16_f16 with P fully lane-local (zero exchange).
// grid 512 (swizzled -> 16 qtiles x 32 bh), 4 waves, QBLK=128, KVB=64, DK=64.
__global__ __launch_bounds__(256,2) void attn_kernel(
    const unsigned short* __restrict__ Q, const unsigned short* __restrict__ K,
    const unsigned short* __restrict__ Vt, unsigned short* __restrict__ O,
    const unsigned int* __restrict__ mp)
{
  __shared__ unsigned short Ksm[2][64*64];
  __shared__ unsigned short Vsm[2][64*64];     // f16 contents
  const int wid = threadIdx.x >> 6, lane = threadIdx.x & 63;
  const int orig = blockIdx.x;
  const int wg = (orig & 7) * 64 + (orig >> 3);    // XCD swizzle (512 % 8 == 0)
  const int qt = wg & 15, bh = wg >> 4;
  const int b = bh >> 4, h = bh & 15;
  const int q0 = qt * 128;
  const int li = lane & 15, lg = lane >> 4;
  const int li7 = li & 7;

  const int rowA = b*2048 + q0 + wid*32 + li;      // lane's q-row, group A
  const int rowB = rowA + 16;                      // group B

  // Q fragments for both q-groups (Wq carries 0.125*log2e -> log2 domain)
  bf16x8 qfA[2], qfB[2];
  {
    const unsigned short* qa = Q + (size_t)rowA*1024 + h*64 + lg*8;
    const unsigned short* qb = Q + (size_t)rowB*1024 + h*64 + lg*8;
    qfA[0] = *(const bf16x8*)qa; qfA[1] = *(const bf16x8*)(qa + 32);
    qfB[0] = *(const bf16x8*)qb; qfB[1] = *(const bf16x8*)(qb + 32);
  }

  f32x4 oaccA[4] = {}, oaccB[4] = {};
  float lrowA = 0.f, lrowB = 0.f;

  const int srow = lane >> 3;
  const int sblk = (lane & 7) ^ srow;    // source-side swizzle for K/V staging

  // stage tile 0
  #pragma unroll
  for(int i=0;i<2;i++){
    int r = wid*16 + i*8 + srow;
    glds16(K  + (size_t)(b*2048 + r)*1024 + h*64 + sblk*8, &Ksm[0][(wid*16 + i*8)*64]);
    glds16(Vt + (size_t)(bh*64 + r)*2048 + sblk*8,         &Vsm[0][(wid*16 + i*8)*64]);
  }
  uint2 mwA = *(const uint2*)&mp[(size_t)rowA*64];
  uint2 mwB = *(const uint2*)&mp[(size_t)rowB*64];
  uint2 mwAn, mwBn;
  __syncthreads();

  int buf = 0;
  for(int t = 0; t < 32; ++t){
    const int kv0 = t * 64;
    if(t < 31){
      #pragma unroll
      for(int i=0;i<2;i++){
        int r = wid*16 + i*8 + srow;
        glds16(K  + (size_t)(b*2048 + kv0 + 64 + r)*1024 + h*64 + sblk*8, &Ksm[buf^1][(wid*16 + i*8)*64]);
        glds16(Vt + (size_t)(bh*64 + r)*2048 + kv0 + 64 + sblk*8,         &Vsm[buf^1][(wid*16 + i*8)*64]);
      }
      mwAn = *(const uint2*)&mp[(size_t)rowA*64 + (size_t)((kv0 + 64) >> 5)];
      mwBn = *(const uint2*)&mp[(size_t)rowB*64 + (size_t)((kv0 + 64) >> 5)];
    }
    // S^T tiles for both q-groups: pX[f][j] = S[q][k=f*16+lg*4+j] (log2 domain)
    f32x4 pA[4], pB[4];
    __builtin_amdgcn_s_setprio(1);
    #pragma unroll
    for(int f=0; f<4; f++){
      f32x4 sa = {0.f,0.f,0.f,0.f}, sb = {0.f,0.f,0.f,0.f};
      #pragma unroll
      for(int kf=0; kf<2; kf++){
        int blk = (kf*4 + lg) ^ li7;
        bf16x8 kfr = *(const bf16x8*)&Ksm[buf][(f*16 + li)*64 + blk*8];
        sa = mfma16(kfr, qfA[kf], sa);
        sb = mfma16(kfr, qfB[kf], sb);
      }
      pA[f] = sa; pB[f] = sb;
    }
    __builtin_amdgcn_s_setprio(0);
    // fused softmax + PV, per k-16 subtile f: P stays lane-local (A-frag of 16x16x16)
    #pragma unroll
    for(int f=0; f<4; f++){
      unsigned int wA = (f < 2) ? mwA.x : mwA.y;
      unsigned int wB = (f < 2) ? mwB.x : mwB.y;
      float eA[4], eB[4];
      #pragma unroll
      for(int j=0;j<4;j++){
        unsigned int bitA = (wA >> ((f & 1)*16 + lg*4 + j)) & 1u;
        unsigned int bitB = (wB >> ((f & 1)*16 + lg*4 + j)) & 1u;
        float vA = exp2v(pA[f][j]);
        float vB = exp2v(pB[f][j]);
        eA[j] = bitA ? 0.f : vA;
        eB[j] = bitB ? 0.f : vB;
      }
      lrowA += (eA[0] + eA[1]) + (eA[2] + eA[3]);
      lrowB += (eB[0] + eB[1]) + (eB[2] + eB[3]);
      union { f16x2 h2[2]; f16x4 v; } ua, ub;
      ua.h2[0] = pkrtz(eA[0], eA[1]);
      ua.h2[1] = pkrtz(eA[2], eA[3]);
      ub.h2[0] = pkrtz(eB[0], eB[1]);
      ub.h2[1] = pkrtz(eB[2], eB[3]);
      const int blk = (f*2 + (lg >> 1)) ^ li7;
      const int sub = (lg & 1)*4;
      __builtin_amdgcn_s_setprio(1);
      #pragma unroll
      for(int dt=0; dt<4; dt++){
        f16x4 vf = *(const f16x4*)&Vsm[buf][(dt*16 + li)*64 + blk*8 + sub];
        oaccA[dt] = mfma16h(ua.v, vf, oaccA[dt]);
        oaccB[dt] = mfma16h(ub.v, vf, oaccB[dt]);
      }
      __builtin_amdgcn_s_setprio(0);
    }
    __syncthreads();
    mwA = mwAn; mwB = mwBn;
    buf ^= 1;
  }
  // reduce lane-partial sums (lanes sharing li), normalize, store both groups
  float rsA = lrowA, rsB = lrowB;
  rsA += __shfl_xor(rsA, 16); rsA += __shfl_xor(rsA, 32);
  rsB += __shfl_xor(rsB, 16); rsB += __shfl_xor(rsB, 32);
  float invA = 1.0f / rsA;               // valid for q-row (group A, index li)
  float invB = 1.0f / rsB;
  #pragma unroll
  for(int r=0;r<4;r++){
    float ioA = __shfl(invA, lg*4 + r);
    float ioB = __shfl(invB, lg*4 + r);
    size_t rbA = (size_t)(b*2048 + q0 + wid*32 + lg*4 + r);
    size_t rbB = rbA + 16;
    #pragma unroll
    for(int dt=0; dt<4; dt++){
      O[rbA*1024 + h*64 + 16*dt + li] = f2bf(oaccA[dt][r] * ioA);
      O[rbB*1024 + h*64 + 16*dt + li] = f2bf(oaccB[dt][r] * ioB);
    }
  }
}

// ---------- launch ----------
extern "C" void kernel_launch(void* const* d_in, const int* in_sizes, int n_in,
                              void* d_out, int out_size, void* d_ws, size_t ws_size,
                              hipStream_t stream)
{
  const float* q_in = (const float*)d_in[0];
  const float* k_in = (const float*)d_in[1];
  const float* v_in = (const float*)d_in[2];
  const unsigned char* mask = (const unsigned char*)d_in[3];
  const float* Wq = (const float*)d_in[4];
  const float* Wk = (const float*)d_in[5];
  const float* Wv = (const float*)d_in[6];
  const float* Wo = (const float*)d_in[7];

  char* ws = (char*)d_ws;
  const size_t MB = 1024*1024;
  unsigned short* XQ = (unsigned short*)(ws + 256);           // 8 MB
  unsigned short* XK = (unsigned short*)(ws + 256 + 8*MB);    // 8 MB
  unsigned short* XV = (unsigned short*)(ws + 256 + 16*MB);   // 8 MB
  unsigned short* WT = (unsigned short*)(ws + 256 + 24*MB);   // 8 MB (4 matrices)
  unsigned short* Qb = (unsigned short*)(ws + 256 + 32*MB);   // 8 MB
  unsigned short* Kb = (unsigned short*)(ws + 256 + 40*MB);   // 8 MB
  unsigned short* Vt = (unsigned short*)(ws + 256 + 48*MB);   // 8 MB (f16, transposed, from GEMM)
  unsigned short* Ob = XQ;                                    // attention output (bf16)
  // packed mask lives in d_out (16 MB f32): consumed by attn, then the final
  // GEMM overwrites all of d_out.  Rewritten fully every call -> deterministic.
  unsigned int* mpk  = (unsigned int*)d_out;                  // 1 MB

  cvt3t_kernel<<<dim3(2048,4), 256, 0, stream>>>(q_in, k_in, v_in, XQ,
                                                 Wq, Wk, Wv, Wo, WT);
  gemm_bt<0><<<dim3(32,8,4), 256, 0, stream>>>(XQ, XK, XV,
                                               WT, WT + 1048576, WT + 2097152,
                                               Qb, Kb, Vt, nullptr,
                                               mask, mpk);
  attn_kernel<<<512, 256, 0, stream>>>(Qb, Kb, Vt, Ob, mpk);
  gemm_bt<1><<<dim3(32,8,1), 256, 0, stream>>>(Ob, Ob, Ob,
                                               WT + 3*1048576, WT + 3*1048576, WT + 3*1048576,
                                               nullptr, nullptr, nullptr, (float*)d_out,
                                               nullptr, nullptr);
}

// Round 13
// 140.115 us; speedup vs baseline: 1.1290x; 1.1290x over previous
//
#include <hip/hip_runtime.h>
#include <hip/hip_bf16.h>

// ---------- types ----------
typedef float f32x4 __attribute__((ext_vector_type(4)));
typedef __bf16 bf16x8 __attribute__((ext_vector_type(8)));
typedef _Float16 f16x2 __attribute__((ext_vector_type(2)));
typedef _Float16 f16x4 __attribute__((ext_vector_type(4)));

// fp32 -> bf16 RNE
__device__ __forceinline__ unsigned short f2bf(float f){
  unsigned int u = __builtin_bit_cast(unsigned int, f);
  u += 0x7fffu + ((u >> 16) & 1u);
  return (unsigned short)(u >> 16);
}
__device__ __forceinline__ float bf2f(unsigned short h){
  return __builtin_bit_cast(float, (unsigned int)h << 16);
}

// packed f32x2 -> f16x2 (v_cvt_pkrtz_f16_f32), with type-identity fix
__device__ __forceinline__ f16x2 pkrtz(float a, float b){
  return __builtin_bit_cast(f16x2, __builtin_amdgcn_cvt_pkrtz(a, b));
}

__device__ __forceinline__ void glds16(const void* g, void* l){
  __builtin_amdgcn_global_load_lds((const __attribute__((address_space(1))) void*)g,
                                   (__attribute__((address_space(3))) void*)l, 16, 0, 0);
}

__device__ __forceinline__ f32x4 mfma16(bf16x8 a, bf16x8 b, f32x4 c){
  return __builtin_amdgcn_mfma_f32_16x16x32_bf16(a, b, c, 0, 0, 0);
}
__device__ __forceinline__ f32x4 mfma16h(f16x4 a, f16x4 b, f32x4 c){
  return __builtin_amdgcn_mfma_f32_16x16x16f16(a, b, c, 0, 0, 0);
}

#if __has_builtin(__builtin_amdgcn_exp2f)
__device__ __forceinline__ float exp2v(float x){ return __builtin_amdgcn_exp2f(x); }
#else
__device__ __forceinline__ float exp2v(float x){ return exp2f(x); }
#endif

// ---------- kernel: pack mask into bits, self-detecting dtype (1024 blocks) ----------
// 1 row per wave, 32 serial c0 iterations -> pipelines across 4096 resident waves.
__global__ void pack_mask_kernel(const unsigned char* __restrict__ m8,
                                 unsigned int* __restrict__ mp){
  const int wid = threadIdx.x >> 6, lane = threadIdx.x & 63;
  const int row = blockIdx.x * 4 + wid;            // 0..4095 (b*2048+q)
  const unsigned int* w32 = (const unsigned int*)m8;
  int bad = 0;
  #pragma unroll
  for(int c = 0; c < 1024; c += 64) bad |= (w32[c + lane] > 1u);
  const int is32 = !__any(bad);
  const int* m32 = (const int*)m8;
  for(int c0 = 0; c0 < 2048; c0 += 64){
    int mv = is32 ? m32[(size_t)row*2048 + c0 + lane]
                  : (int)m8[(size_t)row*2048 + c0 + lane];
    unsigned long long b = __ballot(mv != 0);
    if(lane == 0){
      mp[(size_t)row*64 + (c0 >> 5)]     = (unsigned int)b;
      mp[(size_t)row*64 + (c0 >> 5) + 1] = (unsigned int)(b >> 32);
    }
  }
}

// ---------- kernel: cvt3 (q/k/v fp32->bf16) + transW fused (y==3 slice) ----------
__global__ void cvt3t_kernel(const float* __restrict__ qs, const float* __restrict__ ks,
                             const float* __restrict__ vs, unsigned short* __restrict__ dst,
                             const float* __restrict__ Wq, const float* __restrict__ Wk,
                             const float* __restrict__ Wv, const float* __restrict__ Wo,
                             unsigned short* __restrict__ WT){
  if(blockIdx.y == 3){
    // transW: W[1024][1024] f32 -> W^T bf16 (Wq scaled by 0.125*log2e)
    if(blockIdx.x >= 1024) return;
    const int wsel = blockIdx.x >> 8, bx = blockIdx.x & 255;
    const float* W = (wsel==0)?Wq:(wsel==1)?Wk:(wsel==2)?Wv:Wo;
    const float scale = (wsel==0) ? 0.1803368801111601f : 1.0f;
    unsigned short* D = WT + (size_t)wsel * 1048576;
    int r0 = (bx >> 4) * 64, c0 = (bx & 15) * 64;
    __shared__ unsigned short T[64][65];
    int t = threadIdx.x;
    {
      int r = t >> 2, cb = (t & 3) * 16;
      const float4* src = (const float4*)(W + (size_t)(r0 + r) * 1024 + (c0 + cb));
      float4 v0 = src[0], v1 = src[1], v2 = src[2], v3 = src[3];
      float vals[16] = {v0.x,v0.y,v0.z,v0.w, v1.x,v1.y,v1.z,v1.w,
                        v2.x,v2.y,v2.z,v2.w, v3.x,v3.y,v3.z,v3.w};
      #pragma unroll
      for(int j=0;j<16;j++) T[cb + j][r] = f2bf(vals[j] * scale);
    }
    __syncthreads();
    {
      int c = t >> 2, rb = (t & 3) * 16;
      union { unsigned short h[16]; uint4 v[2]; } o;
      #pragma unroll
      for(int j=0;j<16;j++) o.h[j] = T[c][rb + j];
      uint4* dp = (uint4*)(D + (size_t)(c0 + c) * 1024 + (r0 + rb));
      dp[0] = o.v[0]; dp[1] = o.v[1];
    }
    return;
  }
  const float* src = (blockIdx.y==0)?qs:(blockIdx.y==1)?ks:vs;
  unsigned short* d = dst + (size_t)blockIdx.y * 4194304;
  int i = blockIdx.x * 256 + threadIdx.x;
  const float4* s = (const float4*)src;
  float4 a = s[2*i], b = s[2*i+1];
  union { unsigned short h[8]; uint4 v; } o;
  o.h[0]=f2bf(a.x); o.h[1]=f2bf(a.y); o.h[2]=f2bf(a.z); o.h[3]=f2bf(a.w);
  o.h[4]=f2bf(b.x); o.h[5]=f2bf(b.y); o.h[6]=f2bf(b.z); o.h[7]=f2bf(b.w);
  ((uint4*)d)[i] = o.v;
}

// ---------- kernel: C[M=4096][N=1024] = A @ BT^T, bf16, 128x128 tile, BK=64 ----------
// (round-8 proven single-buffer version)
// blockIdx.z==2 (OUTF32==0) writes per-head transposed V as F16: Vt[(b*16+h)*64+d][s].
template<int OUTF32>
__global__ __launch_bounds__(256,2) void gemm_bt(
    const unsigned short* __restrict__ A0, const unsigned short* __restrict__ A1, const unsigned short* __restrict__ A2,
    const unsigned short* __restrict__ B0, const unsigned short* __restrict__ B1, const unsigned short* __restrict__ B2,
    unsigned short* __restrict__ C0, unsigned short* __restrict__ C1, unsigned short* __restrict__ C2,
    float* __restrict__ Cf)
{
  const unsigned short* A  = (blockIdx.z==0)?A0:(blockIdx.z==1)?A1:A2;
  const unsigned short* BT = (blockIdx.z==0)?B0:(blockIdx.z==1)?B1:B2;
  unsigned short* C        = (blockIdx.z==0)?C0:(blockIdx.z==1)?C1:C2;
  __shared__ unsigned short Asm[128*64];
  __shared__ unsigned short Bsm[128*64];
  const int wid = threadIdx.x >> 6, lane = threadIdx.x & 63;
  const int m0 = blockIdx.x * 128, n0 = blockIdx.y * 128;
  const int wrow = wid >> 1, wcol = wid & 1;
  const int li = lane & 15, lg = lane >> 4, li7 = lane & 7;
  f32x4 acc[4][4] = {};
  const int sr = lane >> 3;       // 0..7 (row within 8-row chunk)
  const int sc = lane & 7;        // 0..7 (16B block within 128B row)

  for(int kt = 0; kt < 16; ++kt){
    const int kofs = kt * 64;
    #pragma unroll
    for(int i=0;i<4;i++){
      int r = wid*32 + i*8 + sr;
      int blk = sc ^ sr;
      glds16(A  + (size_t)(m0 + r)*1024 + kofs + blk*8, &Asm[(wid*32 + i*8)*64]);
      glds16(BT + (size_t)(n0 + r)*1024 + kofs + blk*8, &Bsm[(wid*32 + i*8)*64]);
    }
    __syncthreads();
    #pragma unroll
    for(int kk=0; kk<2; kk++){
      bf16x8 af[4], bfv[4];
      #pragma unroll
      for(int fm=0; fm<4; fm++){
        int row = wrow*64 + fm*16 + li;
        int blk = (kk*4 + lg) ^ li7;
        af[fm] = *(const bf16x8*)&Asm[row*64 + blk*8];
      }
      #pragma unroll
      for(int fn=0; fn<4; fn++){
        int row = wcol*64 + fn*16 + li;
        int blk = (kk*4 + lg) ^ li7;
        bfv[fn] = *(const bf16x8*)&Bsm[row*64 + blk*8];
      }
      __builtin_amdgcn_s_setprio(1);
      #pragma unroll
      for(int fm=0; fm<4; fm++)
        #pragma unroll
        for(int fn=0; fn<4; fn++)
          acc[fm][fn] = mfma16(af[fm], bfv[fn], acc[fm][fn]);
      __builtin_amdgcn_s_setprio(0);
    }
    __syncthreads();
  }
  if(OUTF32 == 0 && blockIdx.z == 2){
    #pragma unroll
    for(int fm=0; fm<4; fm++){
      #pragma unroll
      for(int fn=0; fn<4; fn++){
        int col  = n0 + wcol*64 + fn*16 + li;        // h*64 + d
        int rowb = m0 + wrow*64 + fm*16 + lg*4;      // b*2048 + s
        int bq = rowb >> 11, s = rowb & 2047;
        union { f16x2 h2[2]; unsigned long long u; } o;
        o.h2[0] = pkrtz(acc[fm][fn][0], acc[fm][fn][1]);
        o.h2[1] = pkrtz(acc[fm][fn][2], acc[fm][fn][3]);
        *(unsigned long long*)&C[((size_t)(bq*16 + (col>>6))*64 + (col&63))*2048 + s] = o.u;
      }
    }
  } else {
    #pragma unroll
    for(int fm=0; fm<4; fm++){
      #pragma unroll
      for(int fn=0; fn<4; fn++){
        int col  = n0 + wcol*64 + fn*16 + li;
        int rowb = m0 + wrow*64 + fm*16 + lg*4;
        #pragma unroll
        for(int r=0;r<4;r++){
          if(OUTF32) Cf[(size_t)(rowb + r)*1024 + col] = acc[fm][fn][r];
          else       C [(size_t)(rowb + r)*1024 + col] = f2bf(acc[fm][fn][r]);
        }
      }
    }
  }
}

// ---------- kernel: flash attention v7 (round-8 proven version, unchanged) ----------
// 16x16 swapped-QK, fixed-exponent softmax, 2 q-tiles per wave (32 q-rows),
// PV via mfma_f32_16x16x16_f16 with P fully lane-local (zero exchange).
// grid 512 (swizzled -> 16 qtiles x 32 bh), 4 waves, QBLK=128, KVB=64, DK=64.
__global__ __launch_bounds__(256,2) void attn_kernel(
    const unsigned short* __restrict__ Q, const unsigned short* __restrict__ K,
    const unsigned short* __restrict__ Vt, unsigned short* __restrict__ O,
    const unsigned int* __restrict__ mp)
{
  __shared__ unsigned short Ksm[2][64*64];
  __shared__ unsigned short Vsm[2][64*64];     // f16 contents
  const int wid = threadIdx.x >> 6, lane = threadIdx.x & 63;
  const int orig = blockIdx.x;
  const int wg = (orig & 7) * 64 + (orig >> 3);    // XCD swizzle (512 % 8 == 0)
  const int qt = wg & 15, bh = wg >> 4;
  const int b = bh >> 4, h = bh & 15;
  const int q0 = qt * 128;
  const int li = lane & 15, lg = lane >> 4;
  const int li7 = li & 7;

  const int rowA = b*2048 + q0 + wid*32 + li;      // lane's q-row, group A
  const int rowB = rowA + 16;                      // group B

  // Q fragments for both q-groups (Wq carries 0.125*log2e -> log2 domain)
  bf16x8 qfA[2], qfB[2];
  {
    const unsigned short* qa = Q + (size_t)rowA*1024 + h*64 + lg*8;
    const unsigned short* qb = Q + (size_t)rowB*1024 + h*64 + lg*8;
    qfA[0] = *(const bf16x8*)qa; qfA[1] = *(const bf16x8*)(qa + 32);
    qfB[0] = *(const bf16x8*)qb; qfB[1] = *(const bf16x8*)(qb + 32);
  }

  f32x4 oaccA[4] = {}, oaccB[4] = {};
  float lrowA = 0.f, lrowB = 0.f;

  const int srow = lane >> 3;
  const int sblk = (lane & 7) ^ srow;    // source-side swizzle for K/V staging

  // stage tile 0
  #pragma unroll
  for(int i=0;i<2;i++){
    int r = wid*16 + i*8 + srow;
    glds16(K  + (size_t)(b*2048 + r)*1024 + h*64 + sblk*8, &Ksm[0][(wid*16 + i*8)*64]);
    glds16(Vt + (size_t)(bh*64 + r)*2048 + sblk*8,         &Vsm[0][(wid*16 + i*8)*64]);
  }
  uint2 mwA = *(const uint2*)&mp[(size_t)rowA*64];
  uint2 mwB = *(const uint2*)&mp[(size_t)rowB*64];
  uint2 mwAn, mwBn;
  __syncthreads();

  int buf = 0;
  for(int t = 0; t < 32; ++t){
    const int kv0 = t * 64;
    if(t < 31){
      #pragma unroll
      for(int i=0;i<2;i++){
        int r = wid*16 + i*8 + srow;
        glds16(K  + (size_t)(b*2048 + kv0 + 64 + r)*1024 + h*64 + sblk*8, &Ksm[buf^1][(wid*16 + i*8)*64]);
        glds16(Vt + (size_t)(bh*64 + r)*2048 + kv0 + 64 + sblk*8,         &Vsm[buf^1][(wid*16 + i*8)*64]);
      }
      mwAn = *(const uint2*)&mp[(size_t)rowA*64 + (size_t)((kv0 + 64) >> 5)];
      mwBn = *(const uint2*)&mp[(size_t)rowB*64 + (size_t)((kv0 + 64) >> 5)];
    }
    // S^T tiles for both q-groups: pX[f][j] = S[q][k=f*16+lg*4+j] (log2 domain)
    f32x4 pA[4], pB[4];
    __builtin_amdgcn_s_setprio(1);
    #pragma unroll
    for(int f=0; f<4; f++){
      f32x4 sa = {0.f,0.f,0.f,0.f}, sb = {0.f,0.f,0.f,0.f};
      #pragma unroll
      for(int kf=0; kf<2; kf++){
        int blk = (kf*4 + lg) ^ li7;
        bf16x8 kfr = *(const bf16x8*)&Ksm[buf][(f*16 + li)*64 + blk*8];
        sa = mfma16(kfr, qfA[kf], sa);
        sb = mfma16(kfr, qfB[kf], sb);
      }
      pA[f] = sa; pB[f] = sb;
    }
    __builtin_amdgcn_s_setprio(0);
    // fused softmax + PV, per k-16 subtile f: P stays lane-local (A-frag of 16x16x16)
    #pragma unroll
    for(int f=0; f<4; f++){
      unsigned int wA = (f < 2) ? mwA.x : mwA.y;
      unsigned int wB = (f < 2) ? mwB.x : mwB.y;
      float eA[4], eB[4];
      #pragma unroll
      for(int j=0;j<4;j++){
        unsigned int bitA = (wA >> ((f & 1)*16 + lg*4 + j)) & 1u;
        unsigned int bitB = (wB >> ((f & 1)*16 + lg*4 + j)) & 1u;
        float vA = exp2v(pA[f][j]);
        float vB = exp2v(pB[f][j]);
        eA[j] = bitA ? 0.f : vA;
        eB[j] = bitB ? 0.f : vB;
      }
      lrowA += (eA[0] + eA[1]) + (eA[2] + eA[3]);
      lrowB += (eB[0] + eB[1]) + (eB[2] + eB[3]);
      union { f16x2 h2[2]; f16x4 v; } ua, ub;
      ua.h2[0] = pkrtz(eA[0], eA[1]);
      ua.h2[1] = pkrtz(eA[2], eA[3]);
      ub.h2[0] = pkrtz(eB[0], eB[1]);
      ub.h2[1] = pkrtz(eB[2], eB[3]);
      const int blk = (f*2 + (lg >> 1)) ^ li7;
      const int sub = (lg & 1)*4;
      __builtin_amdgcn_s_setprio(1);
      #pragma unroll
      for(int dt=0; dt<4; dt++){
        f16x4 vf = *(const f16x4*)&Vsm[buf][(dt*16 + li)*64 + blk*8 + sub];
        oaccA[dt] = mfma16h(ua.v, vf, oaccA[dt]);
        oaccB[dt] = mfma16h(ub.v, vf, oaccB[dt]);
      }
      __builtin_amdgcn_s_setprio(0);
    }
    __syncthreads();
    mwA = mwAn; mwB = mwBn;
    buf ^= 1;
  }
  // reduce lane-partial sums (lanes sharing li), normalize, store both groups
  float rsA = lrowA, rsB = lrowB;
  rsA += __shfl_xor(rsA, 16); rsA += __shfl_xor(rsA, 32);
  rsB += __shfl_xor(rsB, 16); rsB += __shfl_xor(rsB, 32);
  float invA = 1.0f / rsA;               // valid for q-row (group A, index li)
  float invB = 1.0f / rsB;
  #pragma unroll
  for(int r=0;r<4;r++){
    float ioA = __shfl(invA, lg*4 + r);
    float ioB = __shfl(invB, lg*4 + r);
    size_t rbA = (size_t)(b*2048 + q0 + wid*32 + lg*4 + r);
    size_t rbB = rbA + 16;
    #pragma unroll
    for(int dt=0; dt<4; dt++){
      O[rbA*1024 + h*64 + 16*dt + li] = f2bf(oaccA[dt][r] * ioA);
      O[rbB*1024 + h*64 + 16*dt + li] = f2bf(oaccB[dt][r] * ioB);
    }
  }
}

// ---------- launch ----------
extern "C" void kernel_launch(void* const* d_in, const int* in_sizes, int n_in,
                              void* d_out, int out_size, void* d_ws, size_t ws_size,
                              hipStream_t stream)
{
  const float* q_in = (const float*)d_in[0];
  const float* k_in = (const float*)d_in[1];
  const float* v_in = (const float*)d_in[2];
  const unsigned char* mask = (const unsigned char*)d_in[3];
  const float* Wq = (const float*)d_in[4];
  const float* Wk = (const float*)d_in[5];
  const float* Wv = (const float*)d_in[6];
  const float* Wo = (const float*)d_in[7];

  char* ws = (char*)d_ws;
  const size_t MB = 1024*1024;
  unsigned short* XQ = (unsigned short*)(ws + 256);           // 8 MB
  unsigned short* XK = (unsigned short*)(ws + 256 + 8*MB);    // 8 MB
  unsigned short* XV = (unsigned short*)(ws + 256 + 16*MB);   // 8 MB
  unsigned short* WT = (unsigned short*)(ws + 256 + 24*MB);   // 8 MB (4 matrices)
  unsigned short* Qb = (unsigned short*)(ws + 256 + 32*MB);   // 8 MB
  unsigned short* Kb = (unsigned short*)(ws + 256 + 40*MB);   // 8 MB
  unsigned short* Vt = (unsigned short*)(ws + 256 + 48*MB);   // 8 MB (f16, transposed, from GEMM)
  unsigned short* Ob = XQ;                                    // attention output (bf16)
  unsigned int*   mpk= (unsigned int*)XV;                     // packed mask (1 MB, after GEMM reads XV)

  cvt3t_kernel<<<dim3(2048,4), 256, 0, stream>>>(q_in, k_in, v_in, XQ,
                                                 Wq, Wk, Wv, Wo, WT);
  gemm_bt<0><<<dim3(32,8,3), 256, 0, stream>>>(XQ, XK, XV,
                                               WT, WT + 1048576, WT + 2097152,
                                               Qb, Kb, Vt, nullptr);
  pack_mask_kernel<<<1024, 256, 0, stream>>>(mask, mpk);
  attn_kernel<<<512, 256, 0, stream>>>(Qb, Kb, Vt, Ob, mpk);
  gemm_bt<1><<<dim3(32,8,1), 256, 0, stream>>>(Ob, Ob, Ob,
                                               WT + 3*1048576, WT + 3*1048576, WT + 3*1048576,
                                               nullptr, nullptr, nullptr, (float*)d_out);
}